// Round 17
// baseline (521.979 us; speedup 1.0000x reference)
//
#include <hip/hip_runtime.h>
#include <hip/hip_bf16.h>

// out[b,s,o] = sum_k x[b,s,k] * W[o,k] + bias[o],  W[o,k] = sum_d codebook[idx[o,d]] * rot[k,d]
// R17: 2-blocks-per-CU variant. R10/R11 probes showed MFMA (620cy) and mem+sync (580cy) are
// ADDITIVE per phase under a single barrier domain (all waves sync together -> matrix pipe
// idles in every sync window). Fix: 128x128 tile, BK=64, 4 waves (256 thr), 64KB LDS ->
// 2 independent blocks/CU; block A's barrier/read windows hide under block B's MFMA (m114:
// independent waves overlap, time ~ max not sum). Keeps all champion ingredients: literal-
// offset swizzled ds_reads (rows still 128B -> identical swizzle math), gload_lds staging,
// XCD swizzle, rule-18 lgkm(0)+sched_barrier. New simplification: all regions' last reader
// is ph1 -> whole tile T+1 staged at ph0 post-BAR -> ONE barrier per K-tile; vmcnt(0) waits
// only loads issued ~2 phases (~1400cy) earlier (no stall; HBM ~900cy).
// Hazards: stage(T+1)->idle buf whose last reads (T-1.ph1) were lgkm-drained by each wave
// before it reached this barrier; ph1 reads hit current buf (no writer this tile); per-wave
// vmcnt(0)+BAR certifies all waves' staged data. Tail: T+1==NT -> no stage, vmcnt(0) waits
// tile's own loads.

typedef __attribute__((ext_vector_type(8))) __bf16 bf16x8;
typedef __attribute__((ext_vector_type(4))) float f32x4;

#define GLOAD_LDS16(g, l)                                                        \
  __builtin_amdgcn_global_load_lds((__attribute__((address_space(1))) void*)(g), \
                                   (__attribute__((address_space(3))) void*)(l), \
                                   16, 0, 0)

#define SB() __builtin_amdgcn_sched_barrier(0)

// ---------------- conversion kernels ----------------

__global__ __launch_bounds__(256) void cvt_f32_bf16(const float* __restrict__ in,
                                                    __hip_bfloat16* __restrict__ out, int n4) {
  int i = blockIdx.x * 256 + threadIdx.x;
  if (i >= n4) return;
  float4 v = *(const float4*)(in + (size_t)i * 4);
  union { __hip_bfloat16 h[4]; ushort4 u; } o;
  o.h[0] = __float2bfloat16(v.x);
  o.h[1] = __float2bfloat16(v.y);
  o.h[2] = __float2bfloat16(v.z);
  o.h[3] = __float2bfloat16(v.w);
  *(ushort4*)((unsigned short*)out + (size_t)i * 4) = o.u;
}

__global__ __launch_bounds__(256) void dequant_bf16(const int* __restrict__ idx,
                                                    const float* __restrict__ cb,
                                                    __hip_bfloat16* __restrict__ out, int n4) {
  __shared__ __hip_bfloat16 scb[16];
  if (threadIdx.x < 16) scb[threadIdx.x] = __float2bfloat16(cb[threadIdx.x]);
  __syncthreads();
  int i = blockIdx.x * 256 + threadIdx.x;
  if (i >= n4) return;
  int4 v = *(const int4*)(idx + (size_t)i * 4);
  union { __hip_bfloat16 h[4]; ushort4 u; } o;
  o.h[0] = scb[v.x & 15];
  o.h[1] = scb[v.y & 15];
  o.h[2] = scb[v.z & 15];
  o.h[3] = scb[v.w & 15];
  *(ushort4*)((unsigned short*)out + (size_t)i * 4) = o.u;
}

// ------- 128^2 1-barrier-per-tile NT bf16 GEMM, 2 blocks/CU, precomputed LDS offsets -------

template <bool OUT_BF16>
__global__ __launch_bounds__(256, 2) void gemm128(const __hip_bfloat16* __restrict__ A,
                                                  const __hip_bfloat16* __restrict__ B,
                                                  void* __restrict__ Cv,
                                                  const float* __restrict__ bias,
                                                  int M, int N, int K) {
  __shared__ __align__(16) char smem[65536];

  const int nbn = N >> 7;
  const int nwg = (M >> 7) * nbn;
  const int bid0 = blockIdx.x;
  const int cpx = nwg >> 3;  // nwg % 8 == 0 for our shapes -> bijective XCD swizzle
  const int bid = (bid0 & 7) * cpx + (bid0 >> 3);
  const int m0 = (bid / nbn) << 7;
  const int n0 = (bid % nbn) << 7;

  const int tid = (int)threadIdx.x;
  const int lane = tid & 63;
  const int w = tid >> 6;   // wave 0..3
  const int wr = w >> 1;    // 0..1 -> 64 rows
  const int wc = w & 1;     // 0..1 -> 64 cols
  const int fr = lane & 15;
  const int fq = lane >> 4;

  const int srow = lane >> 3;
  const int scol = ((lane & 7) ^ srow) << 3;  // inverse-swizzled col (elements)

  const __hip_bfloat16* Ab = A + (size_t)m0 * K;
  const __hip_bfloat16* Bb = B + (size_t)n0 * K;

  const int NT = K >> 6;

  f32x4 acc[4][4];
#pragma unroll
  for (int i = 0; i < 4; ++i)
#pragma unroll
    for (int j = 0; j < 4; ++j) acc[i][j] = (f32x4){0.f, 0.f, 0.f, 0.f};

  // stage half-tile s = 4*t + kind (0=A rows0-63, 1=A rows64-127, 2=B0, 3=B1); 2 gloads/wave
  auto stage = [&](int s) {
    const int t = s >> 2, kind = s & 3;
    const __hip_bfloat16* g = (kind < 2) ? Ab : Bb;
    char* region = smem + ((kind < 2) ? 0 : 32768) + (t & 1) * 16384 + (kind & 1) * 8192;
    const int grow = (kind & 1) * 64 + w * 16 + srow;
    const int k0 = t << 6;
#pragma unroll
    for (int j = 0; j < 2; ++j)
      GLOAD_LDS16(g + (size_t)(grow + j * 8) * K + (k0 + scol), region + w * 2048 + j * 1024);
  };

  // Precomputed per-lane LDS read bases (swizzle baked in; kk variant in the pointer):
  //   byte(b,mf,kk) = b*16384 + (wr*64+mf*16+fr)*128 + ((kk*64+fq*16)^((fr&7)<<4))
  //                 = [wr*8192 + fr*128 + ((fq^(fr&3))<<4) + 64*(kk^fr2)] + b*16384 + mf*2048
  const int fr2 = (fr >> 2) & 1;
  const int fcol = (fq ^ (fr & 3)) << 4;
  const char* pA0 = smem + wr * 8192 + fr * 128 + fcol + 64 * fr2;
  const char* pA1 = smem + wr * 8192 + fr * 128 + fcol + 64 * (1 - fr2);
  const char* pB0 = smem + 32768 + wc * 8192 + fr * 128 + fcol + 64 * fr2;
  const char* pB1 = smem + 32768 + wc * 8192 + fr * 128 + fcol + 64 * (1 - fr2);

#define LDA(BUF, MF, KK) (*(const bf16x8*)(((KK) ? pA1 : pA0) + (BUF) * 16384 + (MF) * 2048))
#define LDB(BUF, NF, KK) (*(const bf16x8*)(((KK) ? pB1 : pB0) + (BUF) * 16384 + (NF) * 2048))

  // prologue: stage tile 0 (8 gloads/wave); loop ph0's vmcnt(0)+BAR certifies it
  stage(0); stage(1); stage(2); stage(3);

  bf16x8 afA[4], afB[4], bk0[4], bk1[4];

#define TILE_BODY(BUF, T)                                                                     \
  {                                                                                           \
    const bool pf1 = ((T) + 1 < NT);                                                          \
    /* ph0: vmcnt(0) waits tile T's stages (issued ~2 phases ago); BAR; reads k0 post-bar;    \
       stage whole tile T+1 -> idle buf; lgkm; 16 MFMA */                                     \
    asm volatile("s_waitcnt vmcnt(0)" ::: "memory");                                          \
    __builtin_amdgcn_s_barrier();                                                             \
    _Pragma("unroll") for (int mf = 0; mf < 4; ++mf) afA[mf] = LDA(BUF, mf, 0);               \
    _Pragma("unroll") for (int nf = 0; nf < 4; ++nf) bk0[nf] = LDB(BUF, nf, 0);               \
    if (pf1) {                                                                                \
      stage(4 * ((T) + 1) + 0);                                                               \
      stage(4 * ((T) + 1) + 1);                                                               \
      stage(4 * ((T) + 1) + 2);                                                               \
      stage(4 * ((T) + 1) + 3);                                                               \
    }                                                                                         \
    asm volatile("s_waitcnt lgkmcnt(0)");                                                     \
    SB();                                                                                     \
    _Pragma("unroll") for (int nf = 0; nf < 4; ++nf)                                          \
        _Pragma("unroll") for (int mf = 0; mf < 4; ++mf)                                      \
            acc[mf][nf] =                                                                     \
                __builtin_amdgcn_mfma_f32_16x16x32_bf16(afA[mf], bk0[nf], acc[mf][nf], 0, 0, 0); \
    /* ph1 (no barrier): reads k1 (compiler may hide them under ph0's MFMA); lgkm; 16 MFMA */ \
    _Pragma("unroll") for (int mf = 0; mf < 4; ++mf) afB[mf] = LDA(BUF, mf, 1);               \
    _Pragma("unroll") for (int nf = 0; nf < 4; ++nf) bk1[nf] = LDB(BUF, nf, 1);               \
    asm volatile("s_waitcnt lgkmcnt(0)");                                                     \
    SB();                                                                                     \
    _Pragma("unroll") for (int nf = 0; nf < 4; ++nf)                                          \
        _Pragma("unroll") for (int mf = 0; mf < 4; ++mf)                                      \
            acc[mf][nf] =                                                                     \
                __builtin_amdgcn_mfma_f32_16x16x32_bf16(afB[mf], bk1[nf], acc[mf][nf], 0, 0, 0); \
  }

  // T-loop unrolled x2: buffer index is compile-time -> all ds_read offsets are literals
  for (int T = 0; T < NT; T += 2) {
    TILE_BODY(0, T);
    TILE_BODY(1, T + 1);
  }
#undef TILE_BODY
#undef LDA
#undef LDB

  // ---- epilogue: C/D layout col = lane&15 (n-side), row = fq*4 + v (m-side)
  if constexpr (OUT_BF16) {
    __hip_bfloat16* C = (__hip_bfloat16*)Cv;
#pragma unroll
    for (int mi = 0; mi < 4; ++mi)
#pragma unroll
      for (int ni = 0; ni < 4; ++ni) {
        const size_t row = (size_t)(m0 + wr * 64 + mi * 16 + fq * 4);
        const int col = n0 + wc * 64 + ni * 16 + fr;
#pragma unroll
        for (int v = 0; v < 4; ++v) C[(row + v) * N + col] = __float2bfloat16(acc[mi][ni][v]);
      }
  } else {
    float* C = (float*)Cv;
    float bv[4];
#pragma unroll
    for (int ni = 0; ni < 4; ++ni) bv[ni] = bias[n0 + wc * 64 + ni * 16 + fr];
#pragma unroll
    for (int mi = 0; mi < 4; ++mi)
#pragma unroll
      for (int ni = 0; ni < 4; ++ni) {
        const size_t row = (size_t)(m0 + wr * 64 + mi * 16 + fq * 4);
        const int col = n0 + wc * 64 + ni * 16 + fr;
#pragma unroll
        for (int v = 0; v < 4; ++v) C[(row + v) * N + col] = acc[mi][ni][v] + bv[ni];
      }
  }
}

// ---------------- launch ----------------

extern "C" void kernel_launch(void* const* d_in, const int* in_sizes, int n_in,
                              void* d_out, int out_size, void* d_ws, size_t ws_size,
                              hipStream_t stream) {
  const float* x = (const float*)d_in[0];        // [B,S,D] = [4,2048,4096] f32
  const int* indices = (const int*)d_in[1];      // [O,D] = [4096,4096] i32
  const float* codebook = (const float*)d_in[2]; // [16] f32
  const float* rot = (const float*)d_in[3];      // [K,D] = [4096,4096] f32
  const float* bias = (const float*)d_in[4];     // [O] f32
  float* out = (float*)d_out;                    // [B*S, O] f32

  const int D = 4096, O = 4096;
  const int M = in_sizes[0] / D;  // 8192

  char* ws = (char*)d_ws;
  __hip_bfloat16* Xb = (__hip_bfloat16*)ws;                          // 64MB: [M,D] bf16
  __hip_bfloat16* Rb = (__hip_bfloat16*)(ws + ((size_t)64 << 20));   // 32MB: [K,D] bf16
  __hip_bfloat16* Wr = (__hip_bfloat16*)(ws + ((size_t)96 << 20));   // 32MB: [O,D] bf16
  __hip_bfloat16* Wb = (__hip_bfloat16*)(ws + ((size_t)128 << 20));  // 32MB: [O,K] bf16

  cvt_f32_bf16<<<(M * D / 4 + 255) / 256, 256, 0, stream>>>(x, Xb, M * D / 4);
  cvt_f32_bf16<<<(4096 * 4096 / 4 + 255) / 256, 256, 0, stream>>>(rot, Rb, 4096 * 4096 / 4);
  dequant_bf16<<<(4096 * 4096 / 4 + 255) / 256, 256, 0, stream>>>(indices, codebook, Wr,
                                                                  4096 * 4096 / 4);

  // GEMM1: Wb[o,k] = sum_d Wr[o,d] * Rb[k,d]   (4096^3, bf16 out)
  gemm128<true><<<dim3((O / 128) * (4096 / 128)), 256, 0, stream>>>(Wr, Rb, Wb, nullptr, O, 4096,
                                                                    D);
  // GEMM2: out[m,o] = sum_k Xb[m,k] * Wb[o,k] + bias[o]   (8192x4096x4096, f32 out)
  gemm128<false><<<dim3((M / 128) * (O / 128)), 256, 0, stream>>>(Xb, Wb, out, bias, M, O, 4096);
}

// Round 18
// 410.836 us; speedup vs baseline: 1.2705x; 1.2705x over previous
//
#include <hip/hip_runtime.h>
#include <hip/hip_bf16.h>

// out[b,s,o] = sum_k x[b,s,k] * W[o,k] + bias[o],  W[o,k] = sum_d codebook[idx[o,d]] * rot[k,d]
// FINAL = R12/R16 champion (verified 411.9 / 410.9us, absmax 2.0).
// Structure: dequant+convert to bf16 (HBM-floor passes), then two 256x256-tile NT GEMMs:
//   GEMM1 W = Wr @ R^T (4096^3, bf16 out), GEMM2 out = X @ W^T + bias (8192x4096x4096, f32).
// GEMM kernel: BK=64, 8 waves (2Mx4N), 16x16x32 MFMA, 4 phases/K-tile with ONE barrier/phase
// (reads pre-barrier where certified, stage post-barrier), counted vmcnt(4) boundary,
// rule-18 lgkm(0)+sched_barrier before each MFMA cluster, T2 LDS XOR-swizzle realized as
// PRECOMPUTED PER-LANE BASE POINTERS (all ds_read offsets are literals, zero per-read VALU),
// T-loop unrolled x2 for compile-time buffer selection, T1 XCD swizzle.
// Rejected by measurement: setprio (R13 -6%), SGB interleave (R14 -1.7%), phase-merge
// (R15 -1%), 32x32 MFMA (R7 -65%), 128^2 2-blk/CU (R17 -27%), deeper prefetch (R4 null),
// fenced prefetch (R9 null), counted-lgkm (R11 null).
// Probe bounds (R10/R11): MFMA floor 620cy/phase, mem+sync 580cy/phase, additive.

typedef __attribute__((ext_vector_type(8))) __bf16 bf16x8;
typedef __attribute__((ext_vector_type(4))) float f32x4;

#define GLOAD_LDS16(g, l)                                                        \
  __builtin_amdgcn_global_load_lds((__attribute__((address_space(1))) void*)(g), \
                                   (__attribute__((address_space(3))) void*)(l), \
                                   16, 0, 0)

#define SB() __builtin_amdgcn_sched_barrier(0)

// ---------------- conversion kernels ----------------

__global__ __launch_bounds__(256) void cvt_f32_bf16(const float* __restrict__ in,
                                                    __hip_bfloat16* __restrict__ out, int n4) {
  int i = blockIdx.x * 256 + threadIdx.x;
  if (i >= n4) return;
  float4 v = *(const float4*)(in + (size_t)i * 4);
  union { __hip_bfloat16 h[4]; ushort4 u; } o;
  o.h[0] = __float2bfloat16(v.x);
  o.h[1] = __float2bfloat16(v.y);
  o.h[2] = __float2bfloat16(v.z);
  o.h[3] = __float2bfloat16(v.w);
  *(ushort4*)((unsigned short*)out + (size_t)i * 4) = o.u;
}

__global__ __launch_bounds__(256) void dequant_bf16(const int* __restrict__ idx,
                                                    const float* __restrict__ cb,
                                                    __hip_bfloat16* __restrict__ out, int n4) {
  __shared__ __hip_bfloat16 scb[16];
  if (threadIdx.x < 16) scb[threadIdx.x] = __float2bfloat16(cb[threadIdx.x]);
  __syncthreads();
  int i = blockIdx.x * 256 + threadIdx.x;
  if (i >= n4) return;
  int4 v = *(const int4*)(idx + (size_t)i * 4);
  union { __hip_bfloat16 h[4]; ushort4 u; } o;
  o.h[0] = scb[v.x & 15];
  o.h[1] = scb[v.y & 15];
  o.h[2] = scb[v.z & 15];
  o.h[3] = scb[v.w & 15];
  *(ushort4*)((unsigned short*)out + (size_t)i * 4) = o.u;
}

// ---------------- 256^2 4-phase (1-barrier) NT bf16 GEMM, precomputed LDS offsets ----------

template <bool OUT_BF16>
__global__ __launch_bounds__(512, 2) void gemm256(const __hip_bfloat16* __restrict__ A,
                                                  const __hip_bfloat16* __restrict__ B,
                                                  void* __restrict__ Cv,
                                                  const float* __restrict__ bias,
                                                  int M, int N, int K) {
  __shared__ __align__(16) char smem[131072];

  const int nbn = N >> 8;
  const int nwg = (M >> 8) * nbn;
  const int bid0 = blockIdx.x;
  const int cpx = nwg >> 3;  // nwg % 8 == 0 for our shapes -> bijective XCD swizzle
  const int bid = (bid0 & 7) * cpx + (bid0 >> 3);
  const int m0 = (bid / nbn) << 8;
  const int n0 = (bid % nbn) << 8;

  const int tid = (int)threadIdx.x;
  const int lane = tid & 63;
  const int w = tid >> 6;
  const int wr = w >> 2;
  const int wc = w & 3;
  const int fr = lane & 15;
  const int fq = lane >> 4;

  const int srow = lane >> 3;
  const int scol = ((lane & 7) ^ srow) << 3;

  const __hip_bfloat16* Ab = A + (size_t)m0 * K;
  const __hip_bfloat16* Bb = B + (size_t)n0 * K;

  const int NT = K >> 6;

  f32x4 acc[8][4];
#pragma unroll
  for (int i = 0; i < 8; ++i)
#pragma unroll
    for (int j = 0; j < 4; ++j) acc[i][j] = (f32x4){0.f, 0.f, 0.f, 0.f};

  auto stage = [&](int s) {
    const int t = s >> 2, kind = s & 3;
    const __hip_bfloat16* g = (kind < 2) ? Ab : Bb;
    char* region = smem + ((kind < 2) ? 0 : 65536) + (t & 1) * 32768 + (kind & 1) * 16384;
    const int grow = (kind & 1) * 128 + w * 16 + srow;
    const int k0 = t << 6;
#pragma unroll
    for (int j = 0; j < 2; ++j)
      GLOAD_LDS16(g + (size_t)(grow + j * 8) * K + (k0 + scol), region + w * 2048 + j * 1024);
  };

  // Precomputed per-lane LDS read bases (swizzle baked in; kk variant in the pointer):
  //   byte(b,mh,mf,kk) = b*32768 + (wr*128+mh*64+mf*16+fr)*128 + ((kk*64+fq*16)^((fr&7)<<4))
  //                    = [wr*16384 + fr*128 + ((fq^(fr&3))<<4) + 64*(kk^fr2)]  (lane base)
  //                      + b*32768 + mh*8192 + mf*2048                          (literal)
  const int fr2 = (fr >> 2) & 1;
  const int fcol = (fq ^ (fr & 3)) << 4;
  const char* pA0 = smem + wr * 16384 + fr * 128 + fcol + 64 * fr2;
  const char* pA1 = smem + wr * 16384 + fr * 128 + fcol + 64 * (1 - fr2);
  const char* pB0 = smem + 65536 + wc * 8192 + fr * 128 + fcol + 64 * fr2;
  const char* pB1 = smem + 65536 + wc * 8192 + fr * 128 + fcol + 64 * (1 - fr2);

#define LDA(BUF, MH, MF, KK) \
  (*(const bf16x8*)(((KK) ? pA1 : pA0) + (BUF) * 32768 + (MH) * 8192 + (MF) * 2048))
#define LDB(BUF, NF, KK) (*(const bf16x8*)(((KK) ? pB1 : pB0) + (BUF) * 32768 + (NF) * 2048))

  // prologue: tile0 fully + B(1); loop ph0's vmcnt+BAR certifies tile0
  stage(0); stage(1); stage(2); stage(3);
  stage(6); stage(7);

  bf16x8 afA[4], afB[4], bk0[4], bk1[4];

#define TILE_BODY(BUF, T)                                                                     \
  {                                                                                           \
    const bool pf1 = ((T) + 1 < NT);                                                          \
    const bool pf2 = ((T) + 2 < NT);                                                          \
    /* ph0: vmcnt certify; BAR; reads post-bar; stage A0(T+1); lgkm; MFMA */                  \
    if ((T) + 1 == NT) {                                                                      \
      asm volatile("s_waitcnt vmcnt(0)" ::: "memory");                                        \
    } else {                                                                                  \
      asm volatile("s_waitcnt vmcnt(4)" ::: "memory");                                        \
    }                                                                                         \
    __builtin_amdgcn_s_barrier();                                                             \
    _Pragma("unroll") for (int mf = 0; mf < 4; ++mf) afA[mf] = LDA(BUF, 0, mf, 0);            \
    _Pragma("unroll") for (int nf = 0; nf < 4; ++nf) bk0[nf] = LDB(BUF, nf, 0);               \
    if (pf1) stage(4 * ((T) + 1) + 0);                                                        \
    asm volatile("s_waitcnt lgkmcnt(0)");                                                     \
    SB();                                                                                     \
    _Pragma("unroll") for (int nf = 0; nf < 4; ++nf)                                          \
        _Pragma("unroll") for (int mf = 0; mf < 4; ++mf)                                      \
            acc[mf][nf] =                                                                     \
                __builtin_amdgcn_mfma_f32_16x16x32_bf16(afA[mf], bk0[nf], acc[mf][nf], 0, 0, 0); \
    /* ph1: reads pre-bar; stage A1(T+1) post-bar */                                          \
    _Pragma("unroll") for (int mf = 0; mf < 4; ++mf) afB[mf] = LDA(BUF, 0, mf, 1);            \
    _Pragma("unroll") for (int nf = 0; nf < 4; ++nf) bk1[nf] = LDB(BUF, nf, 1);               \
    __builtin_amdgcn_s_barrier();                                                             \
    if (pf1) stage(4 * ((T) + 1) + 1);                                                        \
    asm volatile("s_waitcnt lgkmcnt(0)");                                                     \
    SB();                                                                                     \
    _Pragma("unroll") for (int nf = 0; nf < 4; ++nf)                                          \
        _Pragma("unroll") for (int mf = 0; mf < 4; ++mf)                                      \
            acc[mf][nf] =                                                                     \
                __builtin_amdgcn_mfma_f32_16x16x32_bf16(afB[mf], bk1[nf], acc[mf][nf], 0, 0, 0); \
    /* ph2: reads pre-bar; stage B0(T+2) post-bar */                                          \
    _Pragma("unroll") for (int mf = 0; mf < 4; ++mf) afA[mf] = LDA(BUF, 1, mf, 0);            \
    __builtin_amdgcn_s_barrier();                                                             \
    if (pf2) stage(4 * ((T) + 2) + 2);                                                        \
    asm volatile("s_waitcnt lgkmcnt(0)");                                                     \
    SB();                                                                                     \
    _Pragma("unroll") for (int nf = 0; nf < 4; ++nf)                                          \
        _Pragma("unroll") for (int mf = 0; mf < 4; ++mf)                                      \
            acc[4 + mf][nf] = __builtin_amdgcn_mfma_f32_16x16x32_bf16(afA[mf], bk0[nf],       \
                                                                      acc[4 + mf][nf], 0, 0, 0); \
    /* ph3: reads pre-bar; stage B1(T+2) post-bar */                                          \
    _Pragma("unroll") for (int mf = 0; mf < 4; ++mf) afB[mf] = LDA(BUF, 1, mf, 1);            \
    __builtin_amdgcn_s_barrier();                                                             \
    if (pf2) stage(4 * ((T) + 2) + 3);                                                        \
    asm volatile("s_waitcnt lgkmcnt(0)");                                                     \
    SB();                                                                                     \
    _Pragma("unroll") for (int nf = 0; nf < 4; ++nf)                                          \
        _Pragma("unroll") for (int mf = 0; mf < 4; ++mf)                                      \
            acc[4 + mf][nf] = __builtin_amdgcn_mfma_f32_16x16x32_bf16(afB[mf], bk1[nf],       \
                                                                      acc[4 + mf][nf], 0, 0, 0); \
  }

  // T-loop unrolled x2: buffer index is compile-time -> all ds_read offsets are literals
  for (int T = 0; T < NT; T += 2) {
    TILE_BODY(0, T);
    TILE_BODY(1, T + 1);
  }
#undef TILE_BODY
#undef LDA
#undef LDB

  // ---- epilogue: C/D layout col = lane&15 (n-side), row = fq*4 + v (m-side)
  if constexpr (OUT_BF16) {
    __hip_bfloat16* C = (__hip_bfloat16*)Cv;
#pragma unroll
    for (int mi = 0; mi < 8; ++mi)
#pragma unroll
      for (int ni = 0; ni < 4; ++ni) {
        const size_t row = (size_t)(m0 + wr * 128 + (mi >> 2) * 64 + (mi & 3) * 16 + fq * 4);
        const int col = n0 + wc * 64 + ni * 16 + fr;
#pragma unroll
        for (int v = 0; v < 4; ++v) C[(row + v) * N + col] = __float2bfloat16(acc[mi][ni][v]);
      }
  } else {
    float* C = (float*)Cv;
    float bv[4];
#pragma unroll
    for (int ni = 0; ni < 4; ++ni) bv[ni] = bias[n0 + wc * 64 + ni * 16 + fr];
#pragma unroll
    for (int mi = 0; mi < 8; ++mi)
#pragma unroll
      for (int ni = 0; ni < 4; ++ni) {
        const size_t row = (size_t)(m0 + wr * 128 + (mi >> 2) * 64 + (mi & 3) * 16 + fq * 4);
        const int col = n0 + wc * 64 + ni * 16 + fr;
#pragma unroll
        for (int v = 0; v < 4; ++v) C[(row + v) * N + col] = acc[mi][ni][v] + bv[ni];
      }
  }
}

// ---------------- launch ----------------

extern "C" void kernel_launch(void* const* d_in, const int* in_sizes, int n_in,
                              void* d_out, int out_size, void* d_ws, size_t ws_size,
                              hipStream_t stream) {
  const float* x = (const float*)d_in[0];        // [B,S,D] = [4,2048,4096] f32
  const int* indices = (const int*)d_in[1];      // [O,D] = [4096,4096] i32
  const float* codebook = (const float*)d_in[2]; // [16] f32
  const float* rot = (const float*)d_in[3];      // [K,D] = [4096,4096] f32
  const float* bias = (const float*)d_in[4];     // [O] f32
  float* out = (float*)d_out;                    // [B*S, O] f32

  const int D = 4096, O = 4096;
  const int M = in_sizes[0] / D;  // 8192

  char* ws = (char*)d_ws;
  __hip_bfloat16* Xb = (__hip_bfloat16*)ws;                          // 64MB: [M,D] bf16
  __hip_bfloat16* Rb = (__hip_bfloat16*)(ws + ((size_t)64 << 20));   // 32MB: [K,D] bf16
  __hip_bfloat16* Wr = (__hip_bfloat16*)(ws + ((size_t)96 << 20));   // 32MB: [O,D] bf16
  __hip_bfloat16* Wb = (__hip_bfloat16*)(ws + ((size_t)128 << 20));  // 32MB: [O,K] bf16

  cvt_f32_bf16<<<(M * D / 4 + 255) / 256, 256, 0, stream>>>(x, Xb, M * D / 4);
  cvt_f32_bf16<<<(4096 * 4096 / 4 + 255) / 256, 256, 0, stream>>>(rot, Rb, 4096 * 4096 / 4);
  dequant_bf16<<<(4096 * 4096 / 4 + 255) / 256, 256, 0, stream>>>(indices, codebook, Wr,
                                                                  4096 * 4096 / 4);

  // GEMM1: Wb[o,k] = sum_d Wr[o,d] * Rb[k,d]   (4096^3, bf16 out)
  gemm256<true><<<dim3((O / 256) * (4096 / 256)), 512, 0, stream>>>(Wr, Rb, Wb, nullptr, O, 4096,
                                                                    D);
  // GEMM2: out[m,o] = sum_k Xb[m,k] * Wb[o,k] + bias[o]   (8192x4096x4096, f32 out)
  gemm256<false><<<dim3((M / 256) * (O / 256)), 512, 0, stream>>>(Xb, Wb, out, bias, M, O, 4096);
}